// Round 1
// baseline (1589.778 us; speedup 1.0000x reference)
//
#include <hip/hip_runtime.h>
#include <math.h>

#define N_NODES 50000
#define N_EDGES 800000
#define IN_FEATS 128
#define HIDDEN 64

// --- degrees via atomic float add (integer-valued => deterministic) ---
__global__ __launch_bounds__(256) void deg_kernel(const int* __restrict__ src,
                                                  const int* __restrict__ dst,
                                                  float* __restrict__ deg_out,
                                                  float* __restrict__ deg_in) {
    int e = blockIdx.x * 256 + threadIdx.x;
    if (e < N_EDGES) {
        atomicAdd(&deg_out[src[e]], 1.0f);
        atomicAdd(&deg_in[dst[e]], 1.0f);
    }
}

// --- c = 1/sqrt(max(deg,1)) in place ---
__global__ __launch_bounds__(256) void cnorm_kernel(float* __restrict__ cs,
                                                    float* __restrict__ cd) {
    int v = blockIdx.x * 256 + threadIdx.x;
    if (v < N_NODES) {
        cs[v] = rsqrtf(fmaxf(cs[v], 1.0f));
        cd[v] = rsqrtf(fmaxf(cd[v], 1.0f));
    }
}

// --- y[v,:] = c_src[v] * (h[v,:] @ W)   with W staged in LDS ---
// block = 256 threads = 4 rows x 64 cols
template <int K>
__global__ __launch_bounds__(256) void gemm_scaled_kernel(const float* __restrict__ h,
                                                          const float* __restrict__ c_src,
                                                          const float* __restrict__ W,
                                                          float* __restrict__ y) {
    __shared__ float Ws[K * HIDDEN];
    for (int i = threadIdx.x; i < K * HIDDEN; i += 256) Ws[i] = W[i];
    __syncthreads();
    int row = blockIdx.x * 4 + (threadIdx.x >> 6);
    int col = threadIdx.x & 63;
    if (row >= N_NODES) return;
    const float* hr = h + (long)row * K;
    float acc = 0.0f;
#pragma unroll
    for (int k = 0; k < K; ++k) acc = fmaf(hr[k], Ws[k * HIDDEN + col], acc);
    y[row * HIDDEN + col] = acc * c_src[row];
}

// --- agg[dst[e],:] += y[src[e],:]  (16 lanes/edge, float4 gather) ---
__global__ __launch_bounds__(256) void scatter_kernel(const float* __restrict__ y,
                                                      const int* __restrict__ src,
                                                      const int* __restrict__ dst,
                                                      float* __restrict__ agg) {
    int t = blockIdx.x * 256 + threadIdx.x;
    int e = t >> 4;
    if (e >= N_EDGES) return;
    int j4 = (t & 15) << 2;
    int s = src[e], d = dst[e];
    float4 v = *reinterpret_cast<const float4*>(y + (long)s * HIDDEN + j4);
    float* p = agg + (long)d * HIDDEN + j4;
    atomicAdd(p + 0, v.x);
    atomicAdd(p + 1, v.y);
    atomicAdd(p + 2, v.z);
    atomicAdd(p + 3, v.w);
}

// --- h[t] = relu(c_dst[v]*agg[t] + b1[j]) ---
__global__ __launch_bounds__(256) void relu_bias_kernel(const float* __restrict__ agg,
                                                        const float* __restrict__ c_dst,
                                                        const float* __restrict__ b1,
                                                        float* __restrict__ h) {
    int t = blockIdx.x * 256 + threadIdx.x;
    if (t >= N_NODES * HIDDEN) return;
    int v = t >> 6, j = t & 63;
    h[t] = fmaxf(fmaf(c_dst[v], agg[t], b1[j]), 0.0f);
}

// --- per-node: h = c_dst*agg + b2; a_s = h.Ws; a_d = h.Wd (wave reduce) ---
__global__ __launch_bounds__(256) void node_logit_kernel(const float* __restrict__ agg,
                                                         const float* __restrict__ c_dst,
                                                         const float* __restrict__ b2,
                                                         const float* __restrict__ We,
                                                         float* __restrict__ a_s,
                                                         float* __restrict__ a_d) {
    int v = blockIdx.x * 4 + (threadIdx.x >> 6);
    int j = threadIdx.x & 63;
    if (v >= N_NODES) return;
    float hv = fmaf(c_dst[v], agg[(long)v * HIDDEN + j], b2[j]);
    float ps = hv * We[j];
    float pd = hv * We[HIDDEN + j];
#pragma unroll
    for (int o = 32; o > 0; o >>= 1) {
        ps += __shfl_xor(ps, o, 64);
        pd += __shfl_xor(pd, o, 64);
    }
    if (j == 0) {
        a_s[v] = ps;
        a_d[v] = pd;
    }
}

// --- out[e] = sigmoid(a_s[src] + a_d[dst] + efeat.Wf + be) ---
__global__ __launch_bounds__(256) void edge_out_kernel(const int* __restrict__ src,
                                                       const int* __restrict__ dst,
                                                       const float* __restrict__ efeat,
                                                       const float* __restrict__ We,
                                                       const float* __restrict__ be,
                                                       const float* __restrict__ a_s,
                                                       const float* __restrict__ a_d,
                                                       float* __restrict__ out) {
    int e = blockIdx.x * 256 + threadIdx.x;
    if (e >= N_EDGES) return;
    float logit = a_s[src[e]] + a_d[dst[e]]
                + efeat[(long)e * 3 + 0] * We[2 * HIDDEN + 0]
                + efeat[(long)e * 3 + 1] * We[2 * HIDDEN + 1]
                + efeat[(long)e * 3 + 2] * We[2 * HIDDEN + 2]
                + be[0];
    out[e] = 1.0f / (1.0f + expf(-logit));
}

extern "C" void kernel_launch(void* const* d_in, const int* in_sizes, int n_in,
                              void* d_out, int out_size, void* d_ws, size_t ws_size,
                              hipStream_t stream) {
    const float* x     = (const float*)d_in[0];
    const float* efeat = (const float*)d_in[1];
    const int*   src   = (const int*)d_in[2];
    const int*   dst   = (const int*)d_in[3];
    const float* W1    = (const float*)d_in[4];
    const float* b1    = (const float*)d_in[5];
    const float* W2    = (const float*)d_in[6];
    const float* b2    = (const float*)d_in[7];
    const float* We    = (const float*)d_in[8];
    const float* be    = (const float*)d_in[9];
    float* out = (float*)d_out;

    float* ws    = (float*)d_ws;
    float* c_src = ws;                           // N
    float* c_dst = c_src + N_NODES;              // N
    float* a_s   = c_dst + N_NODES;              // N
    float* a_d   = a_s + N_NODES;                // N
    float* bufA  = a_d + N_NODES;                // N*64
    float* bufB  = bufA + (long)N_NODES * HIDDEN; // N*64

    // degrees -> c_src/c_dst
    hipMemsetAsync(c_src, 0, 2 * N_NODES * sizeof(float), stream);
    deg_kernel<<<(N_EDGES + 255) / 256, 256, 0, stream>>>(src, dst, c_src, c_dst);
    cnorm_kernel<<<(N_NODES + 255) / 256, 256, 0, stream>>>(c_src, c_dst);

    // layer 1: y1 = (x*c_src)@W1 ; agg1 = scatter ; h1 = relu(c_dst*agg1+b1)
    gemm_scaled_kernel<IN_FEATS><<<(N_NODES + 3) / 4, 256, 0, stream>>>(x, c_src, W1, bufA);
    hipMemsetAsync(bufB, 0, (size_t)N_NODES * HIDDEN * sizeof(float), stream);
    scatter_kernel<<<(N_EDGES * 16 + 255) / 256, 256, 0, stream>>>(bufA, src, dst, bufB);
    relu_bias_kernel<<<(N_NODES * HIDDEN + 255) / 256, 256, 0, stream>>>(bufB, c_dst, b1, bufA);

    // layer 2: y2 = (h1*c_src)@W2 ; agg2 = scatter ; fused final h -> a_s/a_d
    gemm_scaled_kernel<HIDDEN><<<(N_NODES + 3) / 4, 256, 0, stream>>>(bufA, c_src, W2, bufB);
    hipMemsetAsync(bufA, 0, (size_t)N_NODES * HIDDEN * sizeof(float), stream);
    scatter_kernel<<<(N_EDGES * 16 + 255) / 256, 256, 0, stream>>>(bufB, src, dst, bufA);
    node_logit_kernel<<<(N_NODES + 3) / 4, 256, 0, stream>>>(bufA, c_dst, b2, We, a_s, a_d);

    // edge output
    edge_out_kernel<<<(N_EDGES + 255) / 256, 256, 0, stream>>>(src, dst, efeat, We, be, a_s, a_d, out);
}

// Round 2
// 474.007 us; speedup vs baseline: 3.3539x; 3.3539x over previous
//
#include <hip/hip_runtime.h>
#include <math.h>

#define N_NODES 50000
#define N_EDGES 800000
#define IN_FEATS 128
#define HIDDEN 64
#define SCAN_THREADS 1024

// --- integer degree histogram ---
__global__ __launch_bounds__(256) void deg_kernel(const int* __restrict__ src,
                                                  const int* __restrict__ dst,
                                                  int* __restrict__ deg_out,
                                                  int* __restrict__ deg_in) {
    int e = blockIdx.x * 256 + threadIdx.x;
    if (e < N_EDGES) {
        atomicAdd(&deg_out[src[e]], 1);
        atomicAdd(&deg_in[dst[e]], 1);
    }
}

// --- c = 1/sqrt(max(deg,1)) ---
__global__ __launch_bounds__(256) void cnorm_kernel(const int* __restrict__ dout,
                                                    const int* __restrict__ din,
                                                    float* __restrict__ cs,
                                                    float* __restrict__ cd) {
    int v = blockIdx.x * 256 + threadIdx.x;
    if (v < N_NODES) {
        cs[v] = rsqrtf(fmaxf((float)dout[v], 1.0f));
        cd[v] = rsqrtf(fmaxf((float)din[v], 1.0f));
    }
}

// --- exclusive prefix sum of deg_in -> offs[N_NODES+1], single block ---
__global__ __launch_bounds__(SCAN_THREADS) void scan_kernel(const int* __restrict__ deg,
                                                            int* __restrict__ offs) {
    __shared__ int sums[SCAN_THREADS];
    const int CH = (N_NODES + SCAN_THREADS - 1) / SCAN_THREADS;
    int t = threadIdx.x;
    int base = t * CH;
    int s = 0;
    for (int i = 0; i < CH; ++i) {
        int idx = base + i;
        if (idx < N_NODES) s += deg[idx];
    }
    sums[t] = s;
    __syncthreads();
    for (int o = 1; o < SCAN_THREADS; o <<= 1) {
        int v = (t >= o) ? sums[t - o] : 0;
        __syncthreads();
        sums[t] += v;
        __syncthreads();
    }
    int run = (t == 0) ? 0 : sums[t - 1];
    for (int i = 0; i < CH; ++i) {
        int idx = base + i;
        if (idx < N_NODES) {
            offs[idx] = run;
            run += deg[idx];
        }
    }
    if (t == SCAN_THREADS - 1) offs[N_NODES] = run;
}

// --- fill CSR: csr_src[offs[dst]+k] = src ---
__global__ __launch_bounds__(256) void bucket_kernel(const int* __restrict__ src,
                                                     const int* __restrict__ dst,
                                                     const int* __restrict__ offs,
                                                     int* __restrict__ cnt,
                                                     int* __restrict__ csr_src) {
    int e = blockIdx.x * 256 + threadIdx.x;
    if (e >= N_EDGES) return;
    int d = dst[e];
    int pos = atomicAdd(&cnt[d], 1);
    csr_src[offs[d] + pos] = src[e];
}

// --- y[v,:] = c_src[v] * (h[v,:] @ W)   with W staged in LDS ---
template <int K>
__global__ __launch_bounds__(256) void gemm_scaled_kernel(const float* __restrict__ h,
                                                          const float* __restrict__ c_src,
                                                          const float* __restrict__ W,
                                                          float* __restrict__ y) {
    __shared__ float Ws[K * HIDDEN];
    for (int i = threadIdx.x; i < K * HIDDEN; i += 256) Ws[i] = W[i];
    __syncthreads();
    int row = blockIdx.x * 4 + (threadIdx.x >> 6);
    int col = threadIdx.x & 63;
    if (row >= N_NODES) return;
    const float* hr = h + (long)row * K;
    float acc = 0.0f;
#pragma unroll
    for (int k = 0; k < K; ++k) acc = fmaf(hr[k], Ws[k * HIDDEN + col], acc);
    y[row * HIDDEN + col] = acc * c_src[row];
}

// --- layer1 aggregate by gather + fused bias/relu: h[v,j] = relu(c_dst[v]*sum + b1[j]) ---
__global__ __launch_bounds__(256) void gather_relu_kernel(const float* __restrict__ y,
                                                          const int* __restrict__ offs,
                                                          const int* __restrict__ csr_src,
                                                          const float* __restrict__ c_dst,
                                                          const float* __restrict__ b1,
                                                          float* __restrict__ h) {
    int v = blockIdx.x * 4 + (threadIdx.x >> 6);
    int j = threadIdx.x & 63;
    if (v >= N_NODES) return;
    int beg = offs[v], end = offs[v + 1];
    float acc = 0.0f;
    for (int k = beg; k < end; ++k) {
        acc += y[(long)csr_src[k] * HIDDEN + j];
    }
    h[(long)v * HIDDEN + j] = fmaxf(fmaf(c_dst[v], acc, b1[j]), 0.0f);
}

// --- layer2 aggregate by gather + fused bias + We dot-products (wave reduce) ---
__global__ __launch_bounds__(256) void gather_logit_kernel(const float* __restrict__ y,
                                                           const int* __restrict__ offs,
                                                           const int* __restrict__ csr_src,
                                                           const float* __restrict__ c_dst,
                                                           const float* __restrict__ b2,
                                                           const float* __restrict__ We,
                                                           float* __restrict__ a_s,
                                                           float* __restrict__ a_d) {
    int v = blockIdx.x * 4 + (threadIdx.x >> 6);
    int j = threadIdx.x & 63;
    if (v >= N_NODES) return;
    int beg = offs[v], end = offs[v + 1];
    float acc = 0.0f;
    for (int k = beg; k < end; ++k) {
        acc += y[(long)csr_src[k] * HIDDEN + j];
    }
    float hv = fmaf(c_dst[v], acc, b2[j]);
    float ps = hv * We[j];
    float pd = hv * We[HIDDEN + j];
#pragma unroll
    for (int o = 32; o > 0; o >>= 1) {
        ps += __shfl_xor(ps, o, 64);
        pd += __shfl_xor(pd, o, 64);
    }
    if (j == 0) {
        a_s[v] = ps;
        a_d[v] = pd;
    }
}

// --- out[e] = sigmoid(a_s[src] + a_d[dst] + efeat.Wf + be) ---
__global__ __launch_bounds__(256) void edge_out_kernel(const int* __restrict__ src,
                                                       const int* __restrict__ dst,
                                                       const float* __restrict__ efeat,
                                                       const float* __restrict__ We,
                                                       const float* __restrict__ be,
                                                       const float* __restrict__ a_s,
                                                       const float* __restrict__ a_d,
                                                       float* __restrict__ out) {
    int e = blockIdx.x * 256 + threadIdx.x;
    if (e >= N_EDGES) return;
    float logit = a_s[src[e]] + a_d[dst[e]]
                + efeat[(long)e * 3 + 0] * We[2 * HIDDEN + 0]
                + efeat[(long)e * 3 + 1] * We[2 * HIDDEN + 1]
                + efeat[(long)e * 3 + 2] * We[2 * HIDDEN + 2]
                + be[0];
    out[e] = 1.0f / (1.0f + expf(-logit));
}

extern "C" void kernel_launch(void* const* d_in, const int* in_sizes, int n_in,
                              void* d_out, int out_size, void* d_ws, size_t ws_size,
                              hipStream_t stream) {
    const float* x     = (const float*)d_in[0];
    const float* efeat = (const float*)d_in[1];
    const int*   src   = (const int*)d_in[2];
    const int*   dst   = (const int*)d_in[3];
    const float* W1    = (const float*)d_in[4];
    const float* b1    = (const float*)d_in[5];
    const float* W2    = (const float*)d_in[6];
    const float* b2    = (const float*)d_in[7];
    const float* We    = (const float*)d_in[8];
    const float* be    = (const float*)d_in[9];
    float* out = (float*)d_out;

    char* ws = (char*)d_ws;
    float* c_src   = (float*)ws;                       ws += N_NODES * 4;
    float* c_dst   = (float*)ws;                       ws += N_NODES * 4;
    float* a_s     = (float*)ws;                       ws += N_NODES * 4;
    float* a_d     = (float*)ws;                       ws += N_NODES * 4;
    int*   deg_out = (int*)ws;                         ws += N_NODES * 4;
    int*   deg_in  = (int*)ws;                         ws += N_NODES * 4;
    int*   cnt     = (int*)ws;                         ws += N_NODES * 4;
    int*   offs    = (int*)ws;                         ws += (N_NODES + 1) * 4;
    int*   csr_src = (int*)ws;                         ws += (size_t)N_EDGES * 4;
    float* bufA    = (float*)ws;                       ws += (size_t)N_NODES * HIDDEN * 4;
    float* bufB    = (float*)ws;                       ws += (size_t)N_NODES * HIDDEN * 4;

    // degrees -> c_src/c_dst ; CSR build
    hipMemsetAsync(deg_out, 0, 3 * N_NODES * sizeof(int), stream);  // deg_out, deg_in, cnt
    deg_kernel<<<(N_EDGES + 255) / 256, 256, 0, stream>>>(src, dst, deg_out, deg_in);
    cnorm_kernel<<<(N_NODES + 255) / 256, 256, 0, stream>>>(deg_out, deg_in, c_src, c_dst);
    scan_kernel<<<1, SCAN_THREADS, 0, stream>>>(deg_in, offs);
    bucket_kernel<<<(N_EDGES + 255) / 256, 256, 0, stream>>>(src, dst, offs, cnt, csr_src);

    // layer 1: y1 = (x*c_src)@W1 ; h1 = relu(c_dst * gather-sum + b1)
    gemm_scaled_kernel<IN_FEATS><<<(N_NODES + 3) / 4, 256, 0, stream>>>(x, c_src, W1, bufA);
    gather_relu_kernel<<<(N_NODES + 3) / 4, 256, 0, stream>>>(bufA, offs, csr_src, c_dst, b1, bufB);

    // layer 2: y2 = (h1*c_src)@W2 ; fused gather + bias + We-dot -> a_s/a_d
    gemm_scaled_kernel<HIDDEN><<<(N_NODES + 3) / 4, 256, 0, stream>>>(bufB, c_src, W2, bufA);
    gather_logit_kernel<<<(N_NODES + 3) / 4, 256, 0, stream>>>(bufA, offs, csr_src, c_dst, b2, We, a_s, a_d);

    // edge output
    edge_out_kernel<<<(N_EDGES + 255) / 256, 256, 0, stream>>>(src, dst, efeat, We, be, a_s, a_d, out);
}

// Round 3
// 311.794 us; speedup vs baseline: 5.0988x; 1.5203x over previous
//
#include <hip/hip_runtime.h>
#include <math.h>
#include <stdint.h>

#define N_NODES 50000
#define N_EDGES 800000
#define IN_FEATS 128
#define HIDDEN 64
#define SCAN_BLK 256
#define SCAN_ELEMS 1024  // 4 per thread

// --- integer degree histogram ---
__global__ __launch_bounds__(256) void deg_kernel(const int* __restrict__ src,
                                                  const int* __restrict__ dst,
                                                  int* __restrict__ deg_out,
                                                  int* __restrict__ deg_in) {
    int e = blockIdx.x * 256 + threadIdx.x;
    if (e < N_EDGES) {
        atomicAdd(&deg_out[src[e]], 1);
        atomicAdd(&deg_in[dst[e]], 1);
    }
}

// --- c = 1/sqrt(max(deg,1)) ---
__global__ __launch_bounds__(256) void cnorm_kernel(const int* __restrict__ dout,
                                                    const int* __restrict__ din,
                                                    float* __restrict__ cs,
                                                    float* __restrict__ cd) {
    int v = blockIdx.x * 256 + threadIdx.x;
    if (v < N_NODES) {
        cs[v] = rsqrtf(fmaxf((float)dout[v], 1.0f));
        cd[v] = rsqrtf(fmaxf((float)din[v], 1.0f));
    }
}

// --- scan stage 1: per-block exclusive scan of 1024 elements, emit block sums ---
__global__ __launch_bounds__(SCAN_BLK) void scan1_kernel(const int* __restrict__ deg,
                                                         int* __restrict__ offs,
                                                         int* __restrict__ bsum) {
    __shared__ int sums[SCAN_BLK];
    int t = threadIdx.x;
    int base = blockIdx.x * SCAN_ELEMS + t * 4;
    int d0 = (base + 0 < N_NODES) ? deg[base + 0] : 0;
    int d1 = (base + 1 < N_NODES) ? deg[base + 1] : 0;
    int d2 = (base + 2 < N_NODES) ? deg[base + 2] : 0;
    int d3 = (base + 3 < N_NODES) ? deg[base + 3] : 0;
    sums[t] = d0 + d1 + d2 + d3;
    __syncthreads();
    for (int o = 1; o < SCAN_BLK; o <<= 1) {
        int v = (t >= o) ? sums[t - o] : 0;
        __syncthreads();
        sums[t] += v;
        __syncthreads();
    }
    int excl = (t == 0) ? 0 : sums[t - 1];
    if (base + 0 < N_NODES) offs[base + 0] = excl;
    if (base + 1 < N_NODES) offs[base + 1] = excl + d0;
    if (base + 2 < N_NODES) offs[base + 2] = excl + d0 + d1;
    if (base + 3 < N_NODES) offs[base + 3] = excl + d0 + d1 + d2;
    if (t == SCAN_BLK - 1) bsum[blockIdx.x] = sums[SCAN_BLK - 1];
}

// --- scan stage 2: single wave exclusive scan of block sums (nb <= 64) ---
__global__ __launch_bounds__(64) void scan2_kernel(int* __restrict__ bsum, int nb) {
    int t = threadIdx.x;
    int v = (t < nb) ? bsum[t] : 0;
    int s = v;
#pragma unroll
    for (int o = 1; o < 64; o <<= 1) {
        int u = __shfl_up(s, o, 64);
        if (t >= o) s += u;
    }
    if (t < nb) bsum[t] = s - v;  // exclusive
}

// --- scan stage 3: add block offsets ---
__global__ __launch_bounds__(256) void scan3_kernel(int* __restrict__ offs,
                                                    const int* __restrict__ bsum) {
    int i = blockIdx.x * 256 + threadIdx.x;
    if (i < N_NODES) offs[i] += bsum[i >> 10];  // SCAN_ELEMS = 1024
    if (i == 0) offs[N_NODES] = N_EDGES;        // every dst < N, total = N_EDGES
}

// --- fill CSR: csr_src[offs[dst]+k] = src ---
__global__ __launch_bounds__(256) void bucket_kernel(const int* __restrict__ src,
                                                     const int* __restrict__ dst,
                                                     const int* __restrict__ offs,
                                                     int* __restrict__ cnt,
                                                     int* __restrict__ csr_src) {
    int e = blockIdx.x * 256 + threadIdx.x;
    if (e >= N_EDGES) return;
    int d = dst[e];
    int pos = atomicAdd(&cnt[d], 1);
    csr_src[offs[d] + pos] = src[e];
}

// --- y[v,:] = c_src[v] * (h[v,:] @ W), W swizzled in LDS as float4 per (k-quad, col) ---
// 256 thr = 4 waves; each wave does 4 rows (register blocked); grid-stride by 16 rows/block
template <int K>
__global__ __launch_bounds__(256) void gemm_scaled_kernel(const float* __restrict__ h,
                                                          const float* __restrict__ c_src,
                                                          const float* __restrict__ W,
                                                          float* __restrict__ y) {
    __shared__ float4 Ws4[(K / 4) * HIDDEN];
    for (int idx = threadIdx.x; idx < (K / 4) * HIDDEN; idx += 256) {
        int k4 = idx >> 6, col = idx & 63;
        Ws4[idx] = make_float4(W[(4 * k4 + 0) * HIDDEN + col], W[(4 * k4 + 1) * HIDDEN + col],
                               W[(4 * k4 + 2) * HIDDEN + col], W[(4 * k4 + 3) * HIDDEN + col]);
    }
    __syncthreads();
    int wid = threadIdx.x >> 6, lane = threadIdx.x & 63;
    // N_NODES = 3125 * 16 exactly: no row tail
    for (int base = blockIdx.x * 16; base < N_NODES; base += gridDim.x * 16) {
        int r0 = base + wid * 4;
        const float* h0 = h + (long)(r0 + 0) * K;
        const float* h1 = h + (long)(r0 + 1) * K;
        const float* h2 = h + (long)(r0 + 2) * K;
        const float* h3 = h + (long)(r0 + 3) * K;
        float acc0 = 0.f, acc1 = 0.f, acc2 = 0.f, acc3 = 0.f;
#pragma unroll
        for (int k4 = 0; k4 < K / 4; ++k4) {
            float4 w = Ws4[k4 * 64 + lane];
            float4 a = *reinterpret_cast<const float4*>(h0 + 4 * k4);
            float4 b = *reinterpret_cast<const float4*>(h1 + 4 * k4);
            float4 c = *reinterpret_cast<const float4*>(h2 + 4 * k4);
            float4 d = *reinterpret_cast<const float4*>(h3 + 4 * k4);
            acc0 = fmaf(a.x, w.x, fmaf(a.y, w.y, fmaf(a.z, w.z, fmaf(a.w, w.w, acc0))));
            acc1 = fmaf(b.x, w.x, fmaf(b.y, w.y, fmaf(b.z, w.z, fmaf(b.w, w.w, acc1))));
            acc2 = fmaf(c.x, w.x, fmaf(c.y, w.y, fmaf(c.z, w.z, fmaf(c.w, w.w, acc2))));
            acc3 = fmaf(d.x, w.x, fmaf(d.y, w.y, fmaf(d.z, w.z, fmaf(d.w, w.w, acc3))));
        }
        y[(long)(r0 + 0) * HIDDEN + lane] = acc0 * c_src[r0 + 0];
        y[(long)(r0 + 1) * HIDDEN + lane] = acc1 * c_src[r0 + 1];
        y[(long)(r0 + 2) * HIDDEN + lane] = acc2 * c_src[r0 + 2];
        y[(long)(r0 + 3) * HIDDEN + lane] = acc3 * c_src[r0 + 3];
    }
}

// --- layer1 aggregate: 4 edges/iter per wave (4 slots x 16 lanes x float4) + bias/relu ---
__global__ __launch_bounds__(256) void gather_relu_kernel(const float* __restrict__ y,
                                                          const int* __restrict__ offs,
                                                          const int* __restrict__ csr_src,
                                                          const float* __restrict__ c_dst,
                                                          const float* __restrict__ b1,
                                                          float* __restrict__ h) {
    int wid = threadIdx.x >> 6, l = threadIdx.x & 63;
    int g = l >> 4, q = l & 15;
    int v = blockIdx.x * 4 + wid;  // grid exact: 12500 * 4 = 50000
    int beg = offs[v], end = offs[v + 1];
    float4 acc = make_float4(0.f, 0.f, 0.f, 0.f);
    int k = beg;
    for (; k + 4 <= end; k += 4) {
        int s = csr_src[k + g];
        float4 vy = *reinterpret_cast<const float4*>(y + (long)s * HIDDEN + q * 4);
        acc.x += vy.x; acc.y += vy.y; acc.z += vy.z; acc.w += vy.w;
    }
    int rem = end - k;
    if (g < rem) {
        int s = csr_src[k + g];
        float4 vy = *reinterpret_cast<const float4*>(y + (long)s * HIDDEN + q * 4);
        acc.x += vy.x; acc.y += vy.y; acc.z += vy.z; acc.w += vy.w;
    }
    // combine the 4 slots: lanes {q, q+16, q+32, q+48}
    acc.x += __shfl_xor(acc.x, 16, 64); acc.y += __shfl_xor(acc.y, 16, 64);
    acc.z += __shfl_xor(acc.z, 16, 64); acc.w += __shfl_xor(acc.w, 16, 64);
    acc.x += __shfl_xor(acc.x, 32, 64); acc.y += __shfl_xor(acc.y, 32, 64);
    acc.z += __shfl_xor(acc.z, 32, 64); acc.w += __shfl_xor(acc.w, 32, 64);
    if (g == 0) {
        float c = c_dst[v];
        float4 b = *reinterpret_cast<const float4*>(b1 + q * 4);
        float4 r;
        r.x = fmaxf(fmaf(c, acc.x, b.x), 0.f);
        r.y = fmaxf(fmaf(c, acc.y, b.y), 0.f);
        r.z = fmaxf(fmaf(c, acc.z, b.z), 0.f);
        r.w = fmaxf(fmaf(c, acc.w, b.w), 0.f);
        *reinterpret_cast<float4*>(h + (long)v * HIDDEN + q * 4) = r;
    }
}

// --- layer2 aggregate + bias + We dot-products -> a_s, a_d ---
__global__ __launch_bounds__(256) void gather_logit_kernel(const float* __restrict__ y,
                                                           const int* __restrict__ offs,
                                                           const int* __restrict__ csr_src,
                                                           const float* __restrict__ c_dst,
                                                           const float* __restrict__ b2,
                                                           const float* __restrict__ We,
                                                           float* __restrict__ a_s,
                                                           float* __restrict__ a_d) {
    int wid = threadIdx.x >> 6, l = threadIdx.x & 63;
    int g = l >> 4, q = l & 15;
    int v = blockIdx.x * 4 + wid;
    int beg = offs[v], end = offs[v + 1];
    float4 acc = make_float4(0.f, 0.f, 0.f, 0.f);
    int k = beg;
    for (; k + 4 <= end; k += 4) {
        int s = csr_src[k + g];
        float4 vy = *reinterpret_cast<const float4*>(y + (long)s * HIDDEN + q * 4);
        acc.x += vy.x; acc.y += vy.y; acc.z += vy.z; acc.w += vy.w;
    }
    int rem = end - k;
    if (g < rem) {
        int s = csr_src[k + g];
        float4 vy = *reinterpret_cast<const float4*>(y + (long)s * HIDDEN + q * 4);
        acc.x += vy.x; acc.y += vy.y; acc.z += vy.z; acc.w += vy.w;
    }
    acc.x += __shfl_xor(acc.x, 16, 64); acc.y += __shfl_xor(acc.y, 16, 64);
    acc.z += __shfl_xor(acc.z, 16, 64); acc.w += __shfl_xor(acc.w, 16, 64);
    acc.x += __shfl_xor(acc.x, 32, 64); acc.y += __shfl_xor(acc.y, 32, 64);
    acc.z += __shfl_xor(acc.z, 32, 64); acc.w += __shfl_xor(acc.w, 32, 64);
    float c = c_dst[v];
    float4 b = *reinterpret_cast<const float4*>(b2 + q * 4);
    float4 ws = *reinterpret_cast<const float4*>(We + q * 4);
    float4 wd = *reinterpret_cast<const float4*>(We + HIDDEN + q * 4);
    float hx = fmaf(c, acc.x, b.x), hy = fmaf(c, acc.y, b.y);
    float hz = fmaf(c, acc.z, b.z), hw = fmaf(c, acc.w, b.w);
    float ps = hx * ws.x + hy * ws.y + hz * ws.z + hw * ws.w;
    float pd = hx * wd.x + hy * wd.y + hz * wd.z + hw * wd.w;
    // reduce within 16-lane group (garbage in slots g>0 never crosses in)
#pragma unroll
    for (int o = 1; o <= 8; o <<= 1) {
        ps += __shfl_xor(ps, o, 64);
        pd += __shfl_xor(pd, o, 64);
    }
    if (l == 0) {
        a_s[v] = ps;
        a_d[v] = pd;
    }
}

// --- out[e] = sigmoid(a_s[src] + a_d[dst] + efeat.Wf + be) ---
__global__ __launch_bounds__(256) void edge_out_kernel(const int* __restrict__ src,
                                                       const int* __restrict__ dst,
                                                       const float* __restrict__ efeat,
                                                       const float* __restrict__ We,
                                                       const float* __restrict__ be,
                                                       const float* __restrict__ a_s,
                                                       const float* __restrict__ a_d,
                                                       float* __restrict__ out) {
    int e = blockIdx.x * 256 + threadIdx.x;
    if (e >= N_EDGES) return;
    float logit = a_s[src[e]] + a_d[dst[e]]
                + efeat[(long)e * 3 + 0] * We[2 * HIDDEN + 0]
                + efeat[(long)e * 3 + 1] * We[2 * HIDDEN + 1]
                + efeat[(long)e * 3 + 2] * We[2 * HIDDEN + 2]
                + be[0];
    out[e] = 1.0f / (1.0f + expf(-logit));
}

extern "C" void kernel_launch(void* const* d_in, const int* in_sizes, int n_in,
                              void* d_out, int out_size, void* d_ws, size_t ws_size,
                              hipStream_t stream) {
    const float* x     = (const float*)d_in[0];
    const float* efeat = (const float*)d_in[1];
    const int*   src   = (const int*)d_in[2];
    const int*   dst   = (const int*)d_in[3];
    const float* W1    = (const float*)d_in[4];
    const float* b1    = (const float*)d_in[5];
    const float* W2    = (const float*)d_in[6];
    const float* b2    = (const float*)d_in[7];
    const float* We    = (const float*)d_in[8];
    const float* be    = (const float*)d_in[9];
    float* out = (float*)d_out;

    // 256B-aligned workspace carve-up (float4 paths require 16B alignment)
    char* p = (char*)d_ws;
    auto alloc = [&](size_t bytes) {
        char* r = p;
        p += (bytes + 255) & ~(size_t)255;
        return r;
    };
    float* c_src   = (float*)alloc((size_t)N_NODES * 4);
    float* c_dst   = (float*)alloc((size_t)N_NODES * 4);
    float* a_s     = (float*)alloc((size_t)N_NODES * 4);
    float* a_d     = (float*)alloc((size_t)N_NODES * 4);
    int*   degs    = (int*)alloc((size_t)3 * N_NODES * 4);  // deg_out | deg_in | cnt
    int*   offs    = (int*)alloc((size_t)(N_NODES + 1) * 4);
    int*   bsum    = (int*)alloc(64 * 4);
    int*   csr_src = (int*)alloc((size_t)N_EDGES * 4);
    float* bufA    = (float*)alloc((size_t)N_NODES * HIDDEN * 4);
    float* bufB    = (float*)alloc((size_t)N_NODES * HIDDEN * 4);
    int* deg_out = degs;
    int* deg_in  = degs + N_NODES;
    int* cnt     = degs + 2 * N_NODES;

    const int NB_SCAN = (N_NODES + SCAN_ELEMS - 1) / SCAN_ELEMS;  // 49

    // degrees -> c_src/c_dst ; CSR build
    hipMemsetAsync(degs, 0, (size_t)3 * N_NODES * 4, stream);
    deg_kernel<<<N_EDGES / 256, 256, 0, stream>>>(src, dst, deg_out, deg_in);
    cnorm_kernel<<<(N_NODES + 255) / 256, 256, 0, stream>>>(deg_out, deg_in, c_src, c_dst);
    scan1_kernel<<<NB_SCAN, SCAN_BLK, 0, stream>>>(deg_in, offs, bsum);
    scan2_kernel<<<1, 64, 0, stream>>>(bsum, NB_SCAN);
    scan3_kernel<<<(N_NODES + 255) / 256, 256, 0, stream>>>(offs, bsum);
    bucket_kernel<<<N_EDGES / 256, 256, 0, stream>>>(src, dst, offs, cnt, csr_src);

    // layer 1: y1 = (x*c_src)@W1 ; h1 = relu(c_dst * gather + b1)
    gemm_scaled_kernel<IN_FEATS><<<1024, 256, 0, stream>>>(x, c_src, W1, bufA);
    gather_relu_kernel<<<N_NODES / 4, 256, 0, stream>>>(bufA, offs, csr_src, c_dst, b1, bufB);

    // layer 2: y2 = (h1*c_src)@W2 ; fused gather + bias + We-dot -> a_s/a_d
    gemm_scaled_kernel<HIDDEN><<<1024, 256, 0, stream>>>(bufB, c_src, W2, bufA);
    gather_logit_kernel<<<N_NODES / 4, 256, 0, stream>>>(bufA, offs, csr_src, c_dst, b2, We, a_s, a_d);

    // edge output
    edge_out_kernel<<<N_EDGES / 256, 256, 0, stream>>>(src, dst, efeat, We, be, a_s, a_d, out);
}